// Round 1
// baseline (1116.693 us; speedup 1.0000x reference)
//
#include <hip/hip_runtime.h>
#include <hip/hip_bf16.h>

#define NTOK   2048      // B*L
#define DMODEL 1024
#define NEXP   8
#define DFF    4096
#define MAXROWS 5120
#define MAXTILES 40

typedef __attribute__((ext_vector_type(8))) short short8;
typedef __attribute__((ext_vector_type(4))) float float4v;

__device__ __forceinline__ unsigned short f2bf(float f) {
  union { float f; unsigned u; } v; v.f = f;
  unsigned r = v.u + 0x7fffu + ((v.u >> 16) & 1u);
  return (unsigned short)(r >> 16);
}
__device__ __forceinline__ float bf2f(unsigned short h) {
  union { unsigned u; float f; } v; v.u = ((unsigned)h) << 16; return v.f;
}
__device__ __forceinline__ void gl_lds16(const void* g, void* l) {
  __builtin_amdgcn_global_load_lds((const __attribute__((address_space(1))) void*)g,
                                   (__attribute__((address_space(3))) void*)l, 16, 0, 0);
}

// ---------------- GEMM: C[M,N] = A[M,K](bf16) x B[N,K]^T(bf16), fp32 acc ---
// EPI: 0 C=acc ; 1 C+=acc ; 2 C=C+acc+R ; 3 Cbf=bf16(gelu(acc))
template<int EPI, int EMAP>
__launch_bounds__(256, 2)
__global__ void gemm_bt(const unsigned short* __restrict__ A,
                        const unsigned short* __restrict__ B0,
                        float* __restrict__ C,
                        unsigned short* __restrict__ Cbf,
                        const float* __restrict__ R,
                        const int N, const int K,
                        const int* __restrict__ tmap, const long estride) {
  const int mtile = blockIdx.y;
  const unsigned short* B = B0;
  if (EMAP) {
    int e = tmap[mtile];
    if (e < 0) return;
    B += (size_t)e * (size_t)estride;
  }
  const int n0 = blockIdx.x * 128;
  const int m0 = mtile * 128;
  __shared__ unsigned short sA[128 * 64];
  __shared__ unsigned short sB[128 * 64];
  const int tid  = threadIdx.x;
  const int w    = tid >> 6;
  const int lane = tid & 63;
  const int quad = lane >> 4;
  const int r16  = lane & 15;
  const int wr   = w >> 1;
  const int wc   = w & 1;
  const int rl   = lane >> 3;   // 0..7
  const int csl  = lane & 7;    // lds chunk slot
  const int cg   = csl ^ rl;    // xor-swizzled global chunk
  float4v acc[4][4];
#pragma unroll
  for (int i = 0; i < 4; ++i)
#pragma unroll
    for (int j = 0; j < 4; ++j) acc[i][j] = float4v{0.f, 0.f, 0.f, 0.f};

  const unsigned short* Ab = A + (size_t)m0 * K + cg * 8;
  const unsigned short* Bb = B + (size_t)n0 * K + cg * 8;

  for (int k0 = 0; k0 < K; k0 += 64) {
    __syncthreads();
#pragma unroll
    for (int i = 0; i < 4; ++i) {
      const int j = w * 4 + i;  // wave-uniform instr index 0..15
      gl_lds16(Ab + (size_t)(j * 8 + rl) * K + k0, (char*)sA + j * 1024);
      gl_lds16(Bb + (size_t)(j * 8 + rl) * K + k0, (char*)sB + j * 1024);
    }
    __syncthreads();
#pragma unroll
    for (int kc = 0; kc < 8; kc += 4) {
      short8 af[4], bq[4];
#pragma unroll
      for (int mt = 0; mt < 4; ++mt) {
        int r = wr * 64 + mt * 16 + r16;
        af[mt] = *(const short8*)(sA + ((r * 8 + ((kc + quad) ^ (r & 7))) * 8));
      }
#pragma unroll
      for (int nt = 0; nt < 4; ++nt) {
        int r = wc * 64 + nt * 16 + r16;
        bq[nt] = *(const short8*)(sB + ((r * 8 + ((kc + quad) ^ (r & 7))) * 8));
      }
#pragma unroll
      for (int mt = 0; mt < 4; ++mt)
#pragma unroll
        for (int nt = 0; nt < 4; ++nt)
          acc[mt][nt] = __builtin_amdgcn_mfma_f32_16x16x32_bf16(af[mt], bq[nt], acc[mt][nt], 0, 0, 0);
    }
  }
#pragma unroll
  for (int mt = 0; mt < 4; ++mt) {
#pragma unroll
    for (int nt = 0; nt < 4; ++nt) {
#pragma unroll
      for (int rg = 0; rg < 4; ++rg) {
        const int m = m0 + wr * 64 + mt * 16 + quad * 4 + rg;
        const int n = n0 + wc * 64 + nt * 16 + r16;
        const size_t idx = (size_t)m * N + n;
        const float v = acc[mt][nt][rg];
        if (EPI == 0) C[idx] = v;
        else if (EPI == 1) C[idx] += v;
        else if (EPI == 2) C[idx] = C[idx] + v + R[idx];
        else {
          float ge = 0.5f * v * (1.0f + erff(v * 0.70710678118654752440f));
          Cbf[idx] = f2bf(ge);
        }
      }
    }
  }
}

// ---------------- fp32 [K,N] -> bf16 [N,K] (hi, optional lo) ----------------
template<int WLO>
__global__ void transpose_w(const float* __restrict__ in, unsigned short* __restrict__ oh,
                            unsigned short* __restrict__ ol, const int K, const int N,
                            const long istride, const long ostride) {
  const int bz = blockIdx.z;
  in += (size_t)bz * istride;
  oh += (size_t)bz * ostride;
  if (WLO) ol += (size_t)bz * ostride;
  __shared__ float t[32][33];
  const int n0 = blockIdx.x * 32;
  const int k0 = blockIdx.y * 32;
  const int tx = threadIdx.x;
  const int ty = threadIdx.y;
#pragma unroll
  for (int i = 0; i < 4; ++i)
    t[ty + i * 8][tx] = in[(size_t)(k0 + ty + i * 8) * N + n0 + tx];
  __syncthreads();
#pragma unroll
  for (int i = 0; i < 4; ++i) {
    float v = t[tx][ty + i * 8];
    size_t o = (size_t)(n0 + ty + i * 8) * K + k0 + tx;
    unsigned short h = f2bf(v);
    oh[o] = h;
    if (WLO) ol[o] = f2bf(v - bf2f(h));
  }
}

// ---------------- LayerNorm over D=1024 -------------------------------------
__global__ void ln_kernel(const float* __restrict__ x, const float* __restrict__ g,
                          const float* __restrict__ b, unsigned short* __restrict__ hi,
                          unsigned short* __restrict__ lo, float* __restrict__ f32o) {
  const int row = blockIdx.x;
  const int tid = threadIdx.x;
  const int w = tid >> 6, lane = tid & 63;
  const float4 v = *(const float4*)(x + (size_t)row * DMODEL + tid * 4);
  float s = v.x + v.y + v.z + v.w;
  float q = v.x * v.x + v.y * v.y + v.z * v.z + v.w * v.w;
#pragma unroll
  for (int o = 32; o; o >>= 1) { s += __shfl_xor(s, o); q += __shfl_xor(q, o); }
  __shared__ float red[8];
  if (lane == 0) { red[w] = s; red[4 + w] = q; }
  __syncthreads();
  s = red[0] + red[1] + red[2] + red[3];
  q = red[4] + red[5] + red[6] + red[7];
  const float mean = s * (1.0f / DMODEL);
  const float var = q * (1.0f / DMODEL) - mean * mean;
  const float rs = rsqrtf(var + 1e-5f);
  const float4 gg = *(const float4*)(g + tid * 4);
  const float4 bb = *(const float4*)(b + tid * 4);
  float y[4];
  y[0] = (v.x - mean) * rs * gg.x + bb.x;
  y[1] = (v.y - mean) * rs * gg.y + bb.y;
  y[2] = (v.z - mean) * rs * gg.z + bb.z;
  y[3] = (v.w - mean) * rs * gg.w + bb.w;
  const size_t base = (size_t)row * DMODEL + tid * 4;
#pragma unroll
  for (int i = 0; i < 4; ++i) {
    unsigned short h = f2bf(y[i]);
    hi[base + i] = h;
    if (lo) lo[base + i] = f2bf(y[i] - bf2f(h));
    if (f32o) f32o[base + i] = y[i];
  }
}

// ---------------- RoPE + layout [B,H,L,hd] ----------------------------------
__global__ void rope_kernel(const float* __restrict__ qkv, float* __restrict__ q_r,
                            float* __restrict__ k_r, float* __restrict__ v_r) {
  const int rowtok = blockIdx.x;
  const int b = rowtok >> 10;
  const int l = rowtok & 1023;
  const int tid = threadIdx.x;
  __shared__ float cb[32], sb[32];
  if (tid < 32) {
    float inv = powf(10000.0f, -(float)tid * (1.0f / 32.0f));
    float ang = (float)l * inv;
    cb[tid] = cosf(ang);
    sb[tid] = sinf(ang);
  }
  __syncthreads();
  const float* src = qkv + (size_t)rowtok * 1536;
#pragma unroll
  for (int it = 0; it < 6; ++it) {
    const int e = tid + it * 256;
    const int hh = e >> 6;
    const int d = e & 63;
    const int dm = d & 31;
    float val = src[e];
    float ov;
    if (hh < 20) {
      float partner = (d < 32) ? -src[e + 32] : src[e - 32];
      ov = val * cb[dm] + partner * sb[dm];
    } else ov = val;
    if (hh < 16)
      q_r[((size_t)(b * 16 + hh) * 1024 + l) * 64 + d] = ov;
    else if (hh < 20)
      k_r[((size_t)(b * 4 + (hh - 16)) * 1024 + l) * 64 + d] = ov;
    else
      v_r[((size_t)(b * 4 + (hh - 20)) * 1024 + l) * 64 + d] = ov;
  }
}

// ---------------- causal attention, online softmax, fp32 --------------------
#define RED6MAX(X) { X = fmaxf(X, __shfl_xor(X,32)); X = fmaxf(X, __shfl_xor(X,16)); X = fmaxf(X, __shfl_xor(X,8)); X = fmaxf(X, __shfl_xor(X,4)); X = fmaxf(X, __shfl_xor(X,2)); X = fmaxf(X, __shfl_xor(X,1)); }
#define RED6SUM(X) { X += __shfl_xor(X,32); X += __shfl_xor(X,16); X += __shfl_xor(X,8); X += __shfl_xor(X,4); X += __shfl_xor(X,2); X += __shfl_xor(X,1); }

__launch_bounds__(256)
__global__ void attn_kernel(const float* __restrict__ q_r, const float* __restrict__ k_r,
                            const float* __restrict__ v_r, unsigned short* __restrict__ ohi,
                            unsigned short* __restrict__ olo) {
  const int blk = blockIdx.x;
  const int bh = blk >> 6;        // 64 q-tiles per (b,h)
  const int qt = blk & 63;
  const int b = bh >> 4;
  const int h = bh & 15;
  const int kvh = h >> 2;         // repeat_interleave: h // 4
  const int q0 = qt * 16;
  const int tid = threadIdx.x;
  const int w = tid >> 6;
  const int lane = tid & 63;
  __shared__ float sQ[16 * 68];
  __shared__ float sK[64 * 68];
  __shared__ float sV[64 * 68];
  __shared__ float sP[4 * 64 * 4];
  {
    const int qi = tid >> 4;
    const int dd = (tid & 15) * 4;
    *(float4*)(sQ + qi * 68 + dd) =
        *(const float4*)(q_r + ((size_t)bh * 1024 + q0 + qi) * 64 + dd);
  }
  float m0v = -__builtin_inff(), m1v = m0v, m2v = m0v, m3v = m0v;
  float l0 = 0.f, l1 = 0.f, l2 = 0.f, l3 = 0.f;
  float a0 = 0.f, a1 = 0.f, a2 = 0.f, a3 = 0.f;
  const int nch = (q0 + 15) / 64 + 1;
  const float* kb_ = k_r + (size_t)(b * 4 + kvh) * 1024 * 64;
  const float* vb_ = v_r + (size_t)(b * 4 + kvh) * 1024 * 64;
  const int qg = q0 + w * 4;
  for (int c = 0; c < nch; ++c) {
    __syncthreads();
    {
      const int rr = tid >> 4;
      const int dd = (tid & 15) * 4;
#pragma unroll
      for (int it = 0; it < 4; ++it) {
        const int j = it * 16 + rr;
        *(float4*)(sK + j * 68 + dd) = *(const float4*)(kb_ + (size_t)(c * 64 + j) * 64 + dd);
        *(float4*)(sV + j * 68 + dd) = *(const float4*)(vb_ + (size_t)(c * 64 + j) * 64 + dd);
      }
    }
    __syncthreads();
    const int kkey = c * 64 + lane;
    float s0 = 0.f, s1 = 0.f, s2 = 0.f, s3 = 0.f;
    const float* kk = sK + lane * 68;
    const float* qb = sQ + (w * 4) * 68;
#pragma unroll
    for (int dv = 0; dv < 16; ++dv) {
      const float4 kv = *(const float4*)(kk + dv * 4);
      const float4 qa = *(const float4*)(qb + dv * 4);
      const float4 qd1 = *(const float4*)(qb + 68 + dv * 4);
      const float4 qd2 = *(const float4*)(qb + 136 + dv * 4);
      const float4 qd3 = *(const float4*)(qb + 204 + dv * 4);
      s0 += kv.x * qa.x + kv.y * qa.y + kv.z * qa.z + kv.w * qa.w;
      s1 += kv.x * qd1.x + kv.y * qd1.y + kv.z * qd1.z + kv.w * qd1.w;
      s2 += kv.x * qd2.x + kv.y * qd2.y + kv.z * qd2.z + kv.w * qd2.w;
      s3 += kv.x * qd3.x + kv.y * qd3.y + kv.z * qd3.z + kv.w * qd3.w;
    }
    const float NEGINF = -__builtin_inff();
    s0 = (kkey <= qg + 0) ? s0 * 0.125f : NEGINF;
    s1 = (kkey <= qg + 1) ? s1 * 0.125f : NEGINF;
    s2 = (kkey <= qg + 2) ? s2 * 0.125f : NEGINF;
    s3 = (kkey <= qg + 3) ? s3 * 0.125f : NEGINF;
    float al0, al1, al2, al3, e0, e1, e2, e3;
    { float mx = s0; RED6MAX(mx); float mn = fmaxf(m0v, mx); al0 = __expf(m0v - mn); e0 = __expf(s0 - mn); float ls = e0; RED6SUM(ls); l0 = l0 * al0 + ls; m0v = mn; }
    { float mx = s1; RED6MAX(mx); float mn = fmaxf(m1v, mx); al1 = __expf(m1v - mn); e1 = __expf(s1 - mn); float ls = e1; RED6SUM(ls); l1 = l1 * al1 + ls; m1v = mn; }
    { float mx = s2; RED6MAX(mx); float mn = fmaxf(m2v, mx); al2 = __expf(m2v - mn); e2 = __expf(s2 - mn); float ls = e2; RED6SUM(ls); l2 = l2 * al2 + ls; m2v = mn; }
    { float mx = s3; RED6MAX(mx); float mn = fmaxf(m3v, mx); al3 = __expf(m3v - mn); e3 = __expf(s3 - mn); float ls = e3; RED6SUM(ls); l3 = l3 * al3 + ls; m3v = mn; }
    *(float4*)(sP + (w * 64 + lane) * 4) = make_float4(e0, e1, e2, e3);
    __syncthreads();
    a0 *= al0; a1 *= al1; a2 *= al2; a3 *= al3;
    const float4* pp = (const float4*)(sP + w * 256);
#pragma unroll 8
    for (int j = 0; j < 64; ++j) {
      const float4 pv = pp[j];
      const float vd = sV[j * 68 + lane];
      a0 += pv.x * vd; a1 += pv.y * vd; a2 += pv.z * vd; a3 += pv.w * vd;
    }
  }
  const int col = h * 64 + lane;
  const size_t orow = (size_t)b * 1024 + q0 + w * 4;
  float ov[4] = { a0 / l0, a1 / l1, a2 / l2, a3 / l3 };
#pragma unroll
  for (int qq = 0; qq < 4; ++qq) {
    unsigned short hh2 = f2bf(ov[qq]);
    ohi[(orow + qq) * DMODEL + col] = hh2;
    olo[(orow + qq) * DMODEL + col] = f2bf(ov[qq] - bf2f(hh2));
  }
}

// ---------------- router: fp32 logits, top-2, gates, counts -----------------
__global__ void router_kernel(const float* __restrict__ h2f, const float* __restrict__ wg,
                              int* __restrict__ tok_e, float* __restrict__ tok_g,
                              int* __restrict__ counts) {
  const int t = blockIdx.x;
  const int lane = threadIdx.x;
  float acc[8] = {0,0,0,0,0,0,0,0};
  const float* hr = h2f + (size_t)t * DMODEL;
  for (int d = lane; d < DMODEL; d += 64) {
    const float hv = hr[d];
    const float4 w0 = *(const float4*)(wg + d * 8);
    const float4 w1_ = *(const float4*)(wg + d * 8 + 4);
    acc[0] += hv * w0.x; acc[1] += hv * w0.y; acc[2] += hv * w0.z; acc[3] += hv * w0.w;
    acc[4] += hv * w1_.x; acc[5] += hv * w1_.y; acc[6] += hv * w1_.z; acc[7] += hv * w1_.w;
  }
#pragma unroll
  for (int e = 0; e < 8; ++e) { RED6SUM(acc[e]); }
  if (lane == 0) {
    int i0 = 0; float v0 = acc[0];
#pragma unroll
    for (int e = 1; e < 8; ++e) if (acc[e] > v0) { v0 = acc[e]; i0 = e; }
    int i1 = -1; float v1 = -__builtin_inff();
#pragma unroll
    for (int e = 0; e < 8; ++e) if (e != i0 && acc[e] > v1) { v1 = acc[e]; i1 = e; }
    const float ex = __expf(v1 - v0);
    const float den = 1.0f + ex;
    tok_e[t * 2] = i0; tok_e[t * 2 + 1] = i1;
    tok_g[t * 2] = 1.0f / den; tok_g[t * 2 + 1] = ex / den;
    atomicAdd(counts + i0, 1);
    atomicAdd(counts + i1, 1);
  }
}

__global__ void finalize_kernel(const int* __restrict__ counts, int* __restrict__ off_pad,
                                int* __restrict__ tile_map, float* __restrict__ lb_out) {
  if (threadIdx.x == 0 && blockIdx.x == 0) {
    int tile = 0, rowoff = 0;
    for (int e = 0; e < NEXP; ++e) {
      off_pad[e] = rowoff;
      const int c = counts[e];
      const int nt = (c + 127) >> 7;
      for (int i = 0; i < nt; ++i) tile_map[tile++] = e;
      rowoff += nt * 128;
    }
    for (; tile < MAXTILES; ++tile) tile_map[tile] = -1;
    float sacc = 0.f;
    for (int e = 0; e < NEXP; ++e) {
      const float cn = (float)counts[e] * (1.0f / 4096.0f);
      const float d = cn - 0.125f;
      sacc += d * d;
    }
    lb_out[0] = sacc * (1.0f / 8.0f);
  }
}

__global__ void scatter_kernel(const int* __restrict__ tok_e, const int* __restrict__ off_pad,
                               int* __restrict__ fill, int* __restrict__ tok_pos,
                               const unsigned short* __restrict__ h2bf, unsigned short* __restrict__ Xg) {
  const int slot = blockIdx.x;
  const int t = slot >> 1;
  __shared__ int sp;
  if (threadIdx.x == 0) {
    const int e = tok_e[slot];
    const int r = atomicAdd(fill + e, 1);
    const int ppos = off_pad[e] + r;
    tok_pos[slot] = ppos;
    sp = ppos;
  }
  __syncthreads();
  const int pos = sp;
  *(uint2*)(Xg + (size_t)pos * DMODEL + threadIdx.x * 4) =
      *(const uint2*)(h2bf + (size_t)t * DMODEL + threadIdx.x * 4);
}

__global__ void combine_kernel(const float* __restrict__ x1, const float* __restrict__ eout,
                               const int* __restrict__ tok_pos, const float* __restrict__ tok_g,
                               float* __restrict__ out) {
  const int t = blockIdx.x;
  const int tid = threadIdx.x;
  const int p0 = tok_pos[t * 2], p1 = tok_pos[t * 2 + 1];
  const float g0 = tok_g[t * 2], g1 = tok_g[t * 2 + 1];
  const size_t o = (size_t)t * DMODEL + tid * 4;
  const float4 a = *(const float4*)(x1 + o);
  const float4 e0 = *(const float4*)(eout + (size_t)p0 * DMODEL + tid * 4);
  const float4 e1 = *(const float4*)(eout + (size_t)p1 * DMODEL + tid * 4);
  float4 r;
  r.x = a.x + g0 * e0.x + g1 * e1.x;
  r.y = a.y + g0 * e0.y + g1 * e1.y;
  r.z = a.z + g0 * e0.z + g1 * e1.z;
  r.w = a.w + g0 * e0.w + g1 * e1.w;
  *(float4*)(out + o) = r;
}

__global__ void init_kernel(int* counts, int* fill) {
  const int t = threadIdx.x;
  if (t < 8) { counts[t] = 0; fill[t] = 0; }
}

extern "C" void kernel_launch(void* const* d_in, const int* in_sizes, int n_in,
                              void* d_out, int out_size, void* d_ws, size_t ws_size,
                              hipStream_t stream) {
  (void)in_sizes; (void)n_in; (void)out_size; (void)ws_size;
  const float* x    = (const float*)d_in[0];
  const float* wq   = (const float*)d_in[1];
  const float* wk   = (const float*)d_in[2];
  const float* wv   = (const float*)d_in[3];
  const float* wo   = (const float*)d_in[4];
  const float* wg   = (const float*)d_in[5];
  const float* w1   = (const float*)d_in[6];
  const float* w2   = (const float*)d_in[7];
  const float* ln1g = (const float*)d_in[8];
  const float* ln1b = (const float*)d_in[9];
  const float* ln2g = (const float*)d_in[10];
  const float* ln2b = (const float*)d_in[11];
  float* out = (float*)d_out;

  char* p = (char*)d_ws;
  auto take = [&](size_t n) { void* r = (void*)p; p += (n + 255) & ~(size_t)255; return r; };
  unsigned short* h1_hi   = (unsigned short*)take((size_t)NTOK * DMODEL * 2);
  unsigned short* h1_lo   = (unsigned short*)take((size_t)NTOK * DMODEL * 2);
  unsigned short* wqkv_hi = (unsigned short*)take((size_t)1536 * 1024 * 2);
  unsigned short* wqkv_lo = (unsigned short*)take((size_t)1536 * 1024 * 2);
  unsigned short* woT_hi  = (unsigned short*)take((size_t)1024 * 1024 * 2);
  unsigned short* woT_lo  = (unsigned short*)take((size_t)1024 * 1024 * 2);
  unsigned short* w1t     = (unsigned short*)take((size_t)NEXP * DFF * DMODEL * 2);
  unsigned short* w2t     = (unsigned short*)take((size_t)NEXP * DMODEL * DFF * 2);
  float* qkv   = (float*)take((size_t)NTOK * 1536 * 4);
  float* q_r   = (float*)take((size_t)2 * 16 * 1024 * 64 * 4);
  float* k_r   = (float*)take((size_t)2 * 4 * 1024 * 64 * 4);
  float* v_r   = (float*)take((size_t)2 * 4 * 1024 * 64 * 4);
  unsigned short* attn_hi = (unsigned short*)take((size_t)NTOK * DMODEL * 2);
  unsigned short* attn_lo = (unsigned short*)take((size_t)NTOK * DMODEL * 2);
  float* x1    = (float*)take((size_t)NTOK * DMODEL * 4);
  float* h2f   = (float*)take((size_t)NTOK * DMODEL * 4);
  unsigned short* h2bf = (unsigned short*)take((size_t)NTOK * DMODEL * 2);
  unsigned short* Xg   = (unsigned short*)take((size_t)MAXROWS * DMODEL * 2);
  unsigned short* hid  = (unsigned short*)take((size_t)MAXROWS * DFF * 2);
  float* eout  = (float*)take((size_t)MAXROWS * DMODEL * 4);
  int*   tok_e   = (int*)take(4096 * 4);
  float* tok_g   = (float*)take(4096 * 4);
  int*   tok_pos = (int*)take(4096 * 4);
  int*   counts  = (int*)take(64);
  int*   fill    = (int*)take(64);
  int*   off_pad = (int*)take(64);
  int*   tile_map = (int*)take(256);

  init_kernel<<<1, 64, 0, stream>>>(counts, fill);
  ln_kernel<<<NTOK, 256, 0, stream>>>(x, ln1g, ln1b, h1_hi, h1_lo, nullptr);
  transpose_w<1><<<dim3(32, 32, 1), dim3(32, 8), 0, stream>>>(wq, wqkv_hi, wqkv_lo, 1024, 1024, 0, 0);
  transpose_w<1><<<dim3(8, 32, 1), dim3(32, 8), 0, stream>>>(wk, wqkv_hi + (size_t)1024 * 1024, wqkv_lo + (size_t)1024 * 1024, 1024, 256, 0, 0);
  transpose_w<1><<<dim3(8, 32, 1), dim3(32, 8), 0, stream>>>(wv, wqkv_hi + (size_t)1280 * 1024, wqkv_lo + (size_t)1280 * 1024, 1024, 256, 0, 0);
  transpose_w<1><<<dim3(32, 32, 1), dim3(32, 8), 0, stream>>>(wo, woT_hi, woT_lo, 1024, 1024, 0, 0);
  transpose_w<0><<<dim3(128, 32, 8), dim3(32, 8), 0, stream>>>(w1, w1t, nullptr, 1024, 4096, (long)1024 * 4096, (long)4096 * 1024);
  transpose_w<0><<<dim3(32, 128, 8), dim3(32, 8), 0, stream>>>(w2, w2t, nullptr, 4096, 1024, (long)4096 * 1024, (long)1024 * 4096);
  // qkv = h1 @ [wq|wk|wv], 4-term split-bf16 for router-path precision
  gemm_bt<0,0><<<dim3(12, 16), 256, 0, stream>>>(h1_hi, wqkv_hi, qkv, nullptr, nullptr, 1536, 1024, nullptr, 0);
  gemm_bt<1,0><<<dim3(12, 16), 256, 0, stream>>>(h1_hi, wqkv_lo, qkv, nullptr, nullptr, 1536, 1024, nullptr, 0);
  gemm_bt<1,0><<<dim3(12, 16), 256, 0, stream>>>(h1_lo, wqkv_hi, qkv, nullptr, nullptr, 1536, 1024, nullptr, 0);
  gemm_bt<1,0><<<dim3(12, 16), 256, 0, stream>>>(h1_lo, wqkv_lo, qkv, nullptr, nullptr, 1536, 1024, nullptr, 0);
  rope_kernel<<<NTOK, 256, 0, stream>>>(qkv, q_r, k_r, v_r);
  attn_kernel<<<2048, 256, 0, stream>>>(q_r, k_r, v_r, attn_hi, attn_lo);
  // x1 = x + attn @ wo, 4-term split
  gemm_bt<0,0><<<dim3(8, 16), 256, 0, stream>>>(attn_hi, woT_hi, x1, nullptr, nullptr, 1024, 1024, nullptr, 0);
  gemm_bt<1,0><<<dim3(8, 16), 256, 0, stream>>>(attn_hi, woT_lo, x1, nullptr, nullptr, 1024, 1024, nullptr, 0);
  gemm_bt<1,0><<<dim3(8, 16), 256, 0, stream>>>(attn_lo, woT_hi, x1, nullptr, nullptr, 1024, 1024, nullptr, 0);
  gemm_bt<2,0><<<dim3(8, 16), 256, 0, stream>>>(attn_lo, woT_lo, x1, nullptr, x, 1024, 1024, nullptr, 0);
  ln_kernel<<<NTOK, 256, 0, stream>>>(x1, ln2g, ln2b, h2bf, nullptr, h2f);
  router_kernel<<<NTOK, 64, 0, stream>>>(h2f, wg, tok_e, tok_g, counts);
  finalize_kernel<<<1, 64, 0, stream>>>(counts, off_pad, tile_map, out + (size_t)NTOK * DMODEL);
  scatter_kernel<<<4096, 256, 0, stream>>>(tok_e, off_pad, fill, tok_pos, h2bf, Xg);
  gemm_bt<3,1><<<dim3(32, MAXTILES), 256, 0, stream>>>(Xg, w1t, nullptr, hid, nullptr, DFF, DMODEL, tile_map, (long)DFF * DMODEL);
  gemm_bt<0,1><<<dim3(8, MAXTILES), 256, 0, stream>>>(hid, w2t, eout, nullptr, nullptr, DMODEL, DFF, tile_map, (long)DMODEL * DFF);
  combine_kernel<<<NTOK, 256, 0, stream>>>(x1, eout, tok_pos, tok_g, out);
}

// Round 2
// 758.144 us; speedup vs baseline: 1.4729x; 1.4729x over previous
//
#include <hip/hip_runtime.h>
#include <hip/hip_bf16.h>

#define NTOK   2048      // B*L
#define DMODEL 1024
#define NEXP   8
#define DFF    4096
#define MAXROWS 5120
#define MAXTILES 40

typedef __attribute__((ext_vector_type(8))) short short8;
typedef __attribute__((ext_vector_type(4))) float float4v;

__device__ __forceinline__ unsigned short f2bf(float f) {
  union { float f; unsigned u; } v; v.f = f;
  unsigned r = v.u + 0x7fffu + ((v.u >> 16) & 1u);
  return (unsigned short)(r >> 16);
}
__device__ __forceinline__ float bf2f(unsigned short h) {
  union { unsigned u; float f; } v; v.u = ((unsigned)h) << 16; return v.f;
}
__device__ __forceinline__ void gl_lds16(const void* g, void* l) {
  __builtin_amdgcn_global_load_lds((const __attribute__((address_space(1))) void*)g,
                                   (__attribute__((address_space(3))) void*)l, 16, 0, 0);
}

// ---------------- GEMM: C[M,N] = A[M,K](bf16) x B[N,K]^T(bf16), fp32 acc ---
// EPI: 0 C=acc ; 3 Cbf=bf16(gelu(acc))
template<int EPI, int EMAP>
__launch_bounds__(256, 2)
__global__ void gemm_bt(const unsigned short* __restrict__ A,
                        const unsigned short* __restrict__ B0,
                        float* __restrict__ C,
                        unsigned short* __restrict__ Cbf,
                        const int N, const int K,
                        const int* __restrict__ tmap, const long estride) {
  const int mtile = blockIdx.y;
  const unsigned short* B = B0;
  if (EMAP) {
    int e = tmap[mtile];
    if (e < 0) return;
    B += (size_t)e * (size_t)estride;
  }
  const int n0 = blockIdx.x * 128;
  const int m0 = mtile * 128;
  __shared__ unsigned short sA[128 * 64];
  __shared__ unsigned short sB[128 * 64];
  const int tid  = threadIdx.x;
  const int w    = tid >> 6;
  const int lane = tid & 63;
  const int quad = lane >> 4;
  const int r16  = lane & 15;
  const int wr   = w >> 1;
  const int wc   = w & 1;
  const int rl   = lane >> 3;
  const int csl  = lane & 7;
  const int cg   = csl ^ rl;
  float4v acc[4][4];
#pragma unroll
  for (int i = 0; i < 4; ++i)
#pragma unroll
    for (int j = 0; j < 4; ++j) acc[i][j] = float4v{0.f, 0.f, 0.f, 0.f};

  const unsigned short* Ab = A + (size_t)m0 * K + cg * 8;
  const unsigned short* Bb = B + (size_t)n0 * K + cg * 8;

  for (int k0 = 0; k0 < K; k0 += 64) {
    __syncthreads();
#pragma unroll
    for (int i = 0; i < 4; ++i) {
      const int j = w * 4 + i;
      gl_lds16(Ab + (size_t)(j * 8 + rl) * K + k0, (char*)sA + j * 1024);
      gl_lds16(Bb + (size_t)(j * 8 + rl) * K + k0, (char*)sB + j * 1024);
    }
    __syncthreads();
#pragma unroll
    for (int kc = 0; kc < 8; kc += 4) {
      short8 af[4], bq[4];
#pragma unroll
      for (int mt = 0; mt < 4; ++mt) {
        int r = wr * 64 + mt * 16 + r16;
        af[mt] = *(const short8*)(sA + ((r * 8 + ((kc + quad) ^ (r & 7))) * 8));
      }
#pragma unroll
      for (int nt = 0; nt < 4; ++nt) {
        int r = wc * 64 + nt * 16 + r16;
        bq[nt] = *(const short8*)(sB + ((r * 8 + ((kc + quad) ^ (r & 7))) * 8));
      }
#pragma unroll
      for (int mt = 0; mt < 4; ++mt)
#pragma unroll
        for (int nt = 0; nt < 4; ++nt)
          acc[mt][nt] = __builtin_amdgcn_mfma_f32_16x16x32_bf16(af[mt], bq[nt], acc[mt][nt], 0, 0, 0);
    }
  }
#pragma unroll
  for (int mt = 0; mt < 4; ++mt) {
#pragma unroll
    for (int nt = 0; nt < 4; ++nt) {
#pragma unroll
      for (int rg = 0; rg < 4; ++rg) {
        const int m = m0 + wr * 64 + mt * 16 + quad * 4 + rg;
        const int n = n0 + wc * 64 + nt * 16 + r16;
        const size_t idx = (size_t)m * N + n;
        const float v = acc[mt][nt][rg];
        if (EPI == 0) C[idx] = v;
        else {
          float ge = 0.5f * v * (1.0f + erff(v * 0.70710678118654752440f));
          Cbf[idx] = f2bf(ge);
        }
      }
    }
  }
}

// ------- split-bf16 GEMM: C = (Ah+Al)x(Bh+Bl)^T, 3 terms, single launch -----
// EPI: 0 C=acc ; 2 C = acc + R
template<int EPI>
__launch_bounds__(256, 2)
__global__ void gemm_split(const unsigned short* __restrict__ Ah,
                           const unsigned short* __restrict__ Al,
                           const unsigned short* __restrict__ Bh,
                           const unsigned short* __restrict__ Bl,
                           float* __restrict__ C, const float* __restrict__ R,
                           const int N, const int K) {
  const int n0 = blockIdx.x * 128;
  const int m0 = blockIdx.y * 128;
  __shared__ unsigned short sAh[128 * 64];
  __shared__ unsigned short sAl[128 * 64];
  __shared__ unsigned short sBh[128 * 64];
  __shared__ unsigned short sBl[128 * 64];
  const int tid  = threadIdx.x;
  const int w    = tid >> 6;
  const int lane = tid & 63;
  const int quad = lane >> 4;
  const int r16  = lane & 15;
  const int wr   = w >> 1;
  const int wc   = w & 1;
  const int rl   = lane >> 3;
  const int csl  = lane & 7;
  const int cg   = csl ^ rl;
  float4v acc[4][4];
#pragma unroll
  for (int i = 0; i < 4; ++i)
#pragma unroll
    for (int j = 0; j < 4; ++j) acc[i][j] = float4v{0.f, 0.f, 0.f, 0.f};

  const size_t aoff = (size_t)m0 * K + cg * 8;
  const size_t boff = (size_t)n0 * K + cg * 8;

  for (int k0 = 0; k0 < K; k0 += 64) {
    __syncthreads();
#pragma unroll
    for (int i = 0; i < 4; ++i) {
      const int j = w * 4 + i;
      const size_t ro = (size_t)(j * 8 + rl) * K + k0;
      gl_lds16(Ah + aoff + ro, (char*)sAh + j * 1024);
      gl_lds16(Al + aoff + ro, (char*)sAl + j * 1024);
      gl_lds16(Bh + boff + ro, (char*)sBh + j * 1024);
      gl_lds16(Bl + boff + ro, (char*)sBl + j * 1024);
    }
    __syncthreads();
#pragma unroll
    for (int kc = 0; kc < 8; kc += 4) {
      short8 afh[4], afl[4], bqh[4], bql[4];
#pragma unroll
      for (int mt = 0; mt < 4; ++mt) {
        int r = wr * 64 + mt * 16 + r16;
        int o = (r * 8 + ((kc + quad) ^ (r & 7))) * 8;
        afh[mt] = *(const short8*)(sAh + o);
        afl[mt] = *(const short8*)(sAl + o);
      }
#pragma unroll
      for (int nt = 0; nt < 4; ++nt) {
        int r = wc * 64 + nt * 16 + r16;
        int o = (r * 8 + ((kc + quad) ^ (r & 7))) * 8;
        bqh[nt] = *(const short8*)(sBh + o);
        bql[nt] = *(const short8*)(sBl + o);
      }
#pragma unroll
      for (int mt = 0; mt < 4; ++mt)
#pragma unroll
        for (int nt = 0; nt < 4; ++nt) {
          acc[mt][nt] = __builtin_amdgcn_mfma_f32_16x16x32_bf16(afh[mt], bqh[nt], acc[mt][nt], 0, 0, 0);
          acc[mt][nt] = __builtin_amdgcn_mfma_f32_16x16x32_bf16(afh[mt], bql[nt], acc[mt][nt], 0, 0, 0);
          acc[mt][nt] = __builtin_amdgcn_mfma_f32_16x16x32_bf16(afl[mt], bqh[nt], acc[mt][nt], 0, 0, 0);
        }
    }
  }
#pragma unroll
  for (int mt = 0; mt < 4; ++mt) {
#pragma unroll
    for (int nt = 0; nt < 4; ++nt) {
#pragma unroll
      for (int rg = 0; rg < 4; ++rg) {
        const int m = m0 + wr * 64 + mt * 16 + quad * 4 + rg;
        const int n = n0 + wc * 64 + nt * 16 + r16;
        const size_t idx = (size_t)m * N + n;
        const float v = acc[mt][nt][rg];
        if (EPI == 0) C[idx] = v;
        else C[idx] = v + R[idx];
      }
    }
  }
}

// ---------------- fp32 [K,N] -> bf16 [N,K] (hi, optional lo) ----------------
template<int WLO>
__global__ void transpose_w(const float* __restrict__ in, unsigned short* __restrict__ oh,
                            unsigned short* __restrict__ ol, const int K, const int N,
                            const long istride, const long ostride) {
  const int bz = blockIdx.z;
  in += (size_t)bz * istride;
  oh += (size_t)bz * ostride;
  if (WLO) ol += (size_t)bz * ostride;
  __shared__ float t[32][33];
  const int n0 = blockIdx.x * 32;
  const int k0 = blockIdx.y * 32;
  const int tx = threadIdx.x;
  const int ty = threadIdx.y;
#pragma unroll
  for (int i = 0; i < 4; ++i)
    t[ty + i * 8][tx] = in[(size_t)(k0 + ty + i * 8) * N + n0 + tx];
  __syncthreads();
#pragma unroll
  for (int i = 0; i < 4; ++i) {
    float v = t[tx][ty + i * 8];
    size_t o = (size_t)(n0 + ty + i * 8) * K + k0 + tx;
    unsigned short h = f2bf(v);
    oh[o] = h;
    if (WLO) ol[o] = f2bf(v - bf2f(h));
  }
}

// ---------------- LayerNorm over D=1024 -------------------------------------
__global__ void ln_kernel(const float* __restrict__ x, const float* __restrict__ g,
                          const float* __restrict__ b, unsigned short* __restrict__ hi,
                          unsigned short* __restrict__ lo, float* __restrict__ f32o) {
  const int row = blockIdx.x;
  const int tid = threadIdx.x;
  const int w = tid >> 6, lane = tid & 63;
  const float4 v = *(const float4*)(x + (size_t)row * DMODEL + tid * 4);
  float s = v.x + v.y + v.z + v.w;
  float q = v.x * v.x + v.y * v.y + v.z * v.z + v.w * v.w;
#pragma unroll
  for (int o = 32; o; o >>= 1) { s += __shfl_xor(s, o); q += __shfl_xor(q, o); }
  __shared__ float red[8];
  if (lane == 0) { red[w] = s; red[4 + w] = q; }
  __syncthreads();
  s = red[0] + red[1] + red[2] + red[3];
  q = red[4] + red[5] + red[6] + red[7];
  const float mean = s * (1.0f / DMODEL);
  const float var = q * (1.0f / DMODEL) - mean * mean;
  const float rs = rsqrtf(var + 1e-5f);
  const float4 gg = *(const float4*)(g + tid * 4);
  const float4 bb = *(const float4*)(b + tid * 4);
  float y[4];
  y[0] = (v.x - mean) * rs * gg.x + bb.x;
  y[1] = (v.y - mean) * rs * gg.y + bb.y;
  y[2] = (v.z - mean) * rs * gg.z + bb.z;
  y[3] = (v.w - mean) * rs * gg.w + bb.w;
  const size_t base = (size_t)row * DMODEL + tid * 4;
#pragma unroll
  for (int i = 0; i < 4; ++i) {
    unsigned short h = f2bf(y[i]);
    hi[base + i] = h;
    if (lo) lo[base + i] = f2bf(y[i] - bf2f(h));
    if (f32o) f32o[base + i] = y[i];
  }
}

// -------- RoPE -> split-bf16 Q [bh][L][64], K [bkvh][L][64] -----------------
__global__ void rope_split(const float* __restrict__ qkv,
                           unsigned short* __restrict__ q_hi, unsigned short* __restrict__ q_lo,
                           unsigned short* __restrict__ k_hi, unsigned short* __restrict__ k_lo) {
  const int rowtok = blockIdx.x;
  const int b = rowtok >> 10;
  const int l = rowtok & 1023;
  const int tid = threadIdx.x;
  __shared__ float cb[32], sb[32];
  if (tid < 32) {
    float inv = powf(10000.0f, -(float)tid * (1.0f / 32.0f));
    float ang = (float)l * inv;
    cb[tid] = cosf(ang);
    sb[tid] = sinf(ang);
  }
  __syncthreads();
  const float* src = qkv + (size_t)rowtok * 1536;
#pragma unroll
  for (int it = 0; it < 5; ++it) {
    const int e = tid + it * 256;
    const int hh = e >> 6;
    const int d = e & 63;
    const int dm = d & 31;
    float val = src[e];
    float partner = (d < 32) ? -src[e + 32] : src[e - 32];
    float ov = val * cb[dm] + partner * sb[dm];
    unsigned short hv = f2bf(ov);
    unsigned short lv = f2bf(ov - bf2f(hv));
    if (hh < 16) {
      size_t idx = ((size_t)(b * 16 + hh) * 1024 + l) * 64 + d;
      q_hi[idx] = hv; q_lo[idx] = lv;
    } else {
      size_t idx = ((size_t)(b * 4 + (hh - 16)) * 1024 + l) * 64 + d;
      k_hi[idx] = hv; k_lo[idx] = lv;
    }
  }
}

// -------- V transpose: qkv v-part [L][64] -> bf16 hi/lo [bkvh][64][L] -------
__global__ void vt_split(const float* __restrict__ qkv,
                         unsigned short* __restrict__ vt_hi, unsigned short* __restrict__ vt_lo) {
  const int bkvh = blockIdx.z;
  const int b = bkvh >> 2;
  const int kvh = bkvh & 3;
  const float* src = qkv + (size_t)b * 1024 * 1536 + 1280 + kvh * 64;
  __shared__ float t[32][33];
  const int l0 = blockIdx.y * 32;
  const int d0 = blockIdx.x * 32;
  const int tx = threadIdx.x;
  const int ty = threadIdx.y;
#pragma unroll
  for (int i = 0; i < 4; ++i)
    t[ty + i * 8][tx] = src[(size_t)(l0 + ty + i * 8) * 1536 + d0 + tx];
  __syncthreads();
#pragma unroll
  for (int i = 0; i < 4; ++i) {
    float v = t[tx][ty + i * 8];
    size_t o = (size_t)bkvh * 65536 + (size_t)(d0 + ty + i * 8) * 1024 + l0 + tx;
    unsigned short h = f2bf(v);
    vt_hi[o] = h;
    vt_lo[o] = f2bf(v - bf2f(h));
  }
}

// ---------------- flash attention, split-bf16 MFMA, fp32 softmax ------------
__launch_bounds__(256, 2)
__global__ void attn_mfma(const unsigned short* __restrict__ q_hi, const unsigned short* __restrict__ q_lo,
                          const unsigned short* __restrict__ k_hi, const unsigned short* __restrict__ k_lo,
                          const unsigned short* __restrict__ vt_hi, const unsigned short* __restrict__ vt_lo,
                          unsigned short* __restrict__ ohi, unsigned short* __restrict__ olo) {
  const int blk = blockIdx.x;
  const int bh = blk & 31;               // (b,h)
  const int qt = 15 - (blk >> 5);        // long tiles dispatch first
  const int b = bh >> 4;
  const int h = bh & 15;
  const int kvbh = b * 4 + (h >> 2);
  const int q0 = qt * 64;
  const int tid = threadIdx.x;
  const int w = tid >> 6;
  const int lane = tid & 63;
  const int quad = lane >> 4;
  const int r16 = lane & 15;
  const int rl = lane >> 3;
  const int csl = lane & 7;
  const int cg = csl ^ rl;

  __shared__ unsigned short sK[2][64 * 64];  // [hi/lo], xor-swizzled rows of 8x16B
  __shared__ unsigned short sV[2][64 * 64];  // V^T: row=d, col=key
  __shared__ unsigned short sP[2][64 * 64];  // row=q, col=key

  // Q A-frags straight from global (A[m=r16][k=ks*32+quad*8+j]); rows w*16+r16
  short8 qfh[2], qfl[2];
  {
    const size_t qrow = ((size_t)bh * 1024 + q0 + w * 16 + r16) * 64 + quad * 8;
    qfh[0] = *(const short8*)(q_hi + qrow);
    qfh[1] = *(const short8*)(q_hi + qrow + 32);
    qfl[0] = *(const short8*)(q_lo + qrow);
    qfl[1] = *(const short8*)(q_lo + qrow + 32);
  }
  float4v O[4];
#pragma unroll
  for (int nt = 0; nt < 4; ++nt) O[nt] = float4v{0.f, 0.f, 0.f, 0.f};
  float m[4], l[4];
#pragma unroll
  for (int rg = 0; rg < 4; ++rg) { m[rg] = -__builtin_inff(); l[rg] = 0.f; }

  const unsigned short* khb = k_hi + (size_t)kvbh * 65536 + cg * 8;
  const unsigned short* klb = k_lo + (size_t)kvbh * 65536 + cg * 8;
  const unsigned short* vhb = vt_hi + (size_t)kvbh * 65536 + cg * 8;
  const unsigned short* vlb = vt_lo + (size_t)kvbh * 65536 + cg * 8;

  for (int c = 0; c <= qt; ++c) {
    __syncthreads();
#pragma unroll
    for (int j = 0; j < 2; ++j) {
      const int i = w * 2 + j;           // instruction index 0..7 (8 rows each)
      const int row = i * 8 + rl;
      gl_lds16(khb + (size_t)(c * 64 + row) * 64, (char*)sK[0] + i * 1024);
      gl_lds16(klb + (size_t)(c * 64 + row) * 64, (char*)sK[1] + i * 1024);
      gl_lds16(vhb + (size_t)row * 1024 + c * 64, (char*)sV[0] + i * 1024);
      gl_lds16(vlb + (size_t)row * 1024 + c * 64, (char*)sV[1] + i * 1024);
    }
    __syncthreads();

    // S = Q K^T (3-term split), C-layout: row=quad*4+rg (q), col=r16 (key), nt over key groups
    float4v S[4];
#pragma unroll
    for (int nt = 0; nt < 4; ++nt) S[nt] = float4v{0.f, 0.f, 0.f, 0.f};
#pragma unroll
    for (int ks = 0; ks < 2; ++ks) {
#pragma unroll
      for (int nt = 0; nt < 4; ++nt) {
        const int r = nt * 16 + r16;
        const int o = (r * 8 + ((ks * 4 + quad) ^ (r & 7))) * 8;
        const short8 kh = *(const short8*)(sK[0] + o);
        const short8 kl = *(const short8*)(sK[1] + o);
        S[nt] = __builtin_amdgcn_mfma_f32_16x16x32_bf16(qfh[ks], kh, S[nt], 0, 0, 0);
        S[nt] = __builtin_amdgcn_mfma_f32_16x16x32_bf16(qfh[ks], kl, S[nt], 0, 0, 0);
        S[nt] = __builtin_amdgcn_mfma_f32_16x16x32_bf16(qfl[ks], kh, S[nt], 0, 0, 0);
      }
    }
    // scale + causal mask (diag chunk only)
    const float NEGINF = -__builtin_inff();
#pragma unroll
    for (int nt = 0; nt < 4; ++nt)
#pragma unroll
      for (int rg = 0; rg < 4; ++rg) S[nt][rg] *= 0.125f;
    if (c == qt) {
#pragma unroll
      for (int nt = 0; nt < 4; ++nt) {
        const int col = nt * 16 + r16;
#pragma unroll
        for (int rg = 0; rg < 4; ++rg) {
          const int row = w * 16 + quad * 4 + rg;
          if (col > row) S[nt][rg] = NEGINF;
        }
      }
    }
    // online softmax
    float alpha[4], lsum[4];
#pragma unroll
    for (int rg = 0; rg < 4; ++rg) {
      float mx = fmaxf(fmaxf(S[0][rg], S[1][rg]), fmaxf(S[2][rg], S[3][rg]));
      mx = fmaxf(mx, __shfl_xor(mx, 1));
      mx = fmaxf(mx, __shfl_xor(mx, 2));
      mx = fmaxf(mx, __shfl_xor(mx, 4));
      mx = fmaxf(mx, __shfl_xor(mx, 8));
      const float mn = fmaxf(m[rg], mx);
      alpha[rg] = __expf(m[rg] - mn);
      m[rg] = mn;
      lsum[rg] = 0.f;
    }
#pragma unroll
    for (int nt = 0; nt < 4; ++nt)
#pragma unroll
      for (int rg = 0; rg < 4; ++rg) {
        const float e = __expf(S[nt][rg] - m[rg]);
        S[nt][rg] = e;
        lsum[rg] += e;
      }
#pragma unroll
    for (int rg = 0; rg < 4; ++rg) {
      float ls = lsum[rg];
      ls += __shfl_xor(ls, 1);
      ls += __shfl_xor(ls, 2);
      ls += __shfl_xor(ls, 4);
      ls += __shfl_xor(ls, 8);
      l[rg] = l[rg] * alpha[rg] + ls;
    }
    // P -> LDS (own wave's rows only; same-wave DS ordering, no barrier)
#pragma unroll
    for (int nt = 0; nt < 4; ++nt) {
      const int key = nt * 16 + r16;
      const int chunk = key >> 3;
#pragma unroll
      for (int rg = 0; rg < 4; ++rg) {
        const int r = w * 16 + quad * 4 + rg;
        const int addr = r * 64 + ((chunk ^ (r & 7)) * 8) + (key & 7);
        const float e = S[nt][rg];
        const unsigned short hv = f2bf(e);
        sP[0][addr] = hv;
        sP[1][addr] = f2bf(e - bf2f(hv));
      }
    }
    // rescale O, then O += P V (3-term split)
#pragma unroll
    for (int nt = 0; nt < 4; ++nt)
#pragma unroll
      for (int rg = 0; rg < 4; ++rg) O[nt][rg] *= alpha[rg];
#pragma unroll
    for (int ks = 0; ks < 2; ++ks) {
      const int rA = w * 16 + r16;
      const int oA = (rA * 8 + ((ks * 4 + quad) ^ (rA & 7))) * 8;
      const short8 ph = *(const short8*)(sP[0] + oA);
      const short8 pl = *(const short8*)(sP[1] + oA);
#pragma unroll
      for (int nt = 0; nt < 4; ++nt) {
        const int rv = nt * 16 + r16;
        const int ov = (rv * 8 + ((ks * 4 + quad) ^ (rv & 7))) * 8;
        const short8 vh = *(const short8*)(sV[0] + ov);
        const short8 vl = *(const short8*)(sV[1] + ov);
        O[nt] = __builtin_amdgcn_mfma_f32_16x16x32_bf16(ph, vh, O[nt], 0, 0, 0);
        O[nt] = __builtin_amdgcn_mfma_f32_16x16x32_bf16(ph, vl, O[nt], 0, 0, 0);
        O[nt] = __builtin_amdgcn_mfma_f32_16x16x32_bf16(pl, vh, O[nt], 0, 0, 0);
      }
    }
  }
  // epilogue: divide by l, write hi/lo bf16 into [tok][1024]
#pragma unroll
  for (int nt = 0; nt < 4; ++nt) {
    const int col = h * 64 + nt * 16 + r16;
#pragma unroll
    for (int rg = 0; rg < 4; ++rg) {
      const int row = q0 + w * 16 + quad * 4 + rg;
      const float ovv = O[nt][rg] / l[rg];
      const size_t idx = ((size_t)b * 1024 + row) * DMODEL + col;
      const unsigned short hv = f2bf(ovv);
      ohi[idx] = hv;
      olo[idx] = f2bf(ovv - bf2f(hv));
    }
  }
}

// ---------------- router: fp32 logits, top-2, gates, counts -----------------
#define RED6SUM(X) { X += __shfl_xor(X,32); X += __shfl_xor(X,16); X += __shfl_xor(X,8); X += __shfl_xor(X,4); X += __shfl_xor(X,2); X += __shfl_xor(X,1); }

__global__ void router_kernel(const float* __restrict__ h2f, const float* __restrict__ wg,
                              int* __restrict__ tok_e, float* __restrict__ tok_g,
                              int* __restrict__ counts) {
  const int t = blockIdx.x;
  const int lane = threadIdx.x;
  float acc[8] = {0,0,0,0,0,0,0,0};
  const float* hr = h2f + (size_t)t * DMODEL;
  for (int d = lane; d < DMODEL; d += 64) {
    const float hv = hr[d];
    const float4 w0 = *(const float4*)(wg + d * 8);
    const float4 w1_ = *(const float4*)(wg + d * 8 + 4);
    acc[0] += hv * w0.x; acc[1] += hv * w0.y; acc[2] += hv * w0.z; acc[3] += hv * w0.w;
    acc[4] += hv * w1_.x; acc[5] += hv * w1_.y; acc[6] += hv * w1_.z; acc[7] += hv * w1_.w;
  }
#pragma unroll
  for (int e = 0; e < 8; ++e) { RED6SUM(acc[e]); }
  if (lane == 0) {
    int i0 = 0; float v0 = acc[0];
#pragma unroll
    for (int e = 1; e < 8; ++e) if (acc[e] > v0) { v0 = acc[e]; i0 = e; }
    int i1 = -1; float v1 = -__builtin_inff();
#pragma unroll
    for (int e = 0; e < 8; ++e) if (e != i0 && acc[e] > v1) { v1 = acc[e]; i1 = e; }
    const float ex = __expf(v1 - v0);
    const float den = 1.0f + ex;
    tok_e[t * 2] = i0; tok_e[t * 2 + 1] = i1;
    tok_g[t * 2] = 1.0f / den; tok_g[t * 2 + 1] = ex / den;
    atomicAdd(counts + i0, 1);
    atomicAdd(counts + i1, 1);
  }
}

__global__ void finalize_kernel(const int* __restrict__ counts, int* __restrict__ off_pad,
                                int* __restrict__ tile_map, float* __restrict__ lb_out) {
  if (threadIdx.x == 0 && blockIdx.x == 0) {
    int tile = 0, rowoff = 0;
    for (int e = 0; e < NEXP; ++e) {
      off_pad[e] = rowoff;
      const int c = counts[e];
      const int nt = (c + 127) >> 7;
      for (int i = 0; i < nt; ++i) tile_map[tile++] = e;
      rowoff += nt * 128;
    }
    for (; tile < MAXTILES; ++tile) tile_map[tile] = -1;
    float sacc = 0.f;
    for (int e = 0; e < NEXP; ++e) {
      const float cn = (float)counts[e] * (1.0f / 4096.0f);
      const float d = cn - 0.125f;
      sacc += d * d;
    }
    lb_out[0] = sacc * (1.0f / 8.0f);
  }
}

__global__ void scatter_kernel(const int* __restrict__ tok_e, const int* __restrict__ off_pad,
                               int* __restrict__ fill, int* __restrict__ tok_pos,
                               const unsigned short* __restrict__ h2bf, unsigned short* __restrict__ Xg) {
  const int slot = blockIdx.x;
  const int t = slot >> 1;
  __shared__ int sp;
  if (threadIdx.x == 0) {
    const int e = tok_e[slot];
    const int r = atomicAdd(fill + e, 1);
    const int ppos = off_pad[e] + r;
    tok_pos[slot] = ppos;
    sp = ppos;
  }
  __syncthreads();
  const int pos = sp;
  *(uint2*)(Xg + (size_t)pos * DMODEL + threadIdx.x * 4) =
      *(const uint2*)(h2bf + (size_t)t * DMODEL + threadIdx.x * 4);
}

__global__ void combine_kernel(const float* __restrict__ x1, const float* __restrict__ eout,
                               const int* __restrict__ tok_pos, const float* __restrict__ tok_g,
                               float* __restrict__ out) {
  const int t = blockIdx.x;
  const int tid = threadIdx.x;
  const int p0 = tok_pos[t * 2], p1 = tok_pos[t * 2 + 1];
  const float g0 = tok_g[t * 2], g1 = tok_g[t * 2 + 1];
  const size_t o = (size_t)t * DMODEL + tid * 4;
  const float4 a = *(const float4*)(x1 + o);
  const float4 e0 = *(const float4*)(eout + (size_t)p0 * DMODEL + tid * 4);
  const float4 e1 = *(const float4*)(eout + (size_t)p1 * DMODEL + tid * 4);
  float4 r;
  r.x = a.x + g0 * e0.x + g1 * e1.x;
  r.y = a.y + g0 * e0.y + g1 * e1.y;
  r.z = a.z + g0 * e0.z + g1 * e1.z;
  r.w = a.w + g0 * e0.w + g1 * e1.w;
  *(float4*)(out + o) = r;
}

__global__ void init_kernel(int* counts, int* fill) {
  const int t = threadIdx.x;
  if (t < 8) { counts[t] = 0; fill[t] = 0; }
}

extern "C" void kernel_launch(void* const* d_in, const int* in_sizes, int n_in,
                              void* d_out, int out_size, void* d_ws, size_t ws_size,
                              hipStream_t stream) {
  (void)in_sizes; (void)n_in; (void)out_size; (void)ws_size;
  const float* x    = (const float*)d_in[0];
  const float* wq   = (const float*)d_in[1];
  const float* wk   = (const float*)d_in[2];
  const float* wv   = (const float*)d_in[3];
  const float* wo   = (const float*)d_in[4];
  const float* wg   = (const float*)d_in[5];
  const float* w1   = (const float*)d_in[6];
  const float* w2   = (const float*)d_in[7];
  const float* ln1g = (const float*)d_in[8];
  const float* ln1b = (const float*)d_in[9];
  const float* ln2g = (const float*)d_in[10];
  const float* ln2b = (const float*)d_in[11];
  float* out = (float*)d_out;

  char* p = (char*)d_ws;
  auto take = [&](size_t n) { void* r = (void*)p; p += (n + 255) & ~(size_t)255; return r; };
  unsigned short* h1_hi   = (unsigned short*)take((size_t)NTOK * DMODEL * 2);
  unsigned short* h1_lo   = (unsigned short*)take((size_t)NTOK * DMODEL * 2);
  unsigned short* wqkv_hi = (unsigned short*)take((size_t)1536 * 1024 * 2);
  unsigned short* wqkv_lo = (unsigned short*)take((size_t)1536 * 1024 * 2);
  unsigned short* woT_hi  = (unsigned short*)take((size_t)1024 * 1024 * 2);
  unsigned short* woT_lo  = (unsigned short*)take((size_t)1024 * 1024 * 2);
  unsigned short* w1t     = (unsigned short*)take((size_t)NEXP * DFF * DMODEL * 2);
  unsigned short* w2t     = (unsigned short*)take((size_t)NEXP * DMODEL * DFF * 2);
  float* qkv   = (float*)take((size_t)NTOK * 1536 * 4);
  unsigned short* q_hi  = (unsigned short*)take((size_t)2 * 16 * 1024 * 64 * 2);
  unsigned short* q_lo  = (unsigned short*)take((size_t)2 * 16 * 1024 * 64 * 2);
  unsigned short* k_hi  = (unsigned short*)take((size_t)2 * 4 * 1024 * 64 * 2);
  unsigned short* k_lo  = (unsigned short*)take((size_t)2 * 4 * 1024 * 64 * 2);
  unsigned short* vt_hi = (unsigned short*)take((size_t)2 * 4 * 1024 * 64 * 2);
  unsigned short* vt_lo = (unsigned short*)take((size_t)2 * 4 * 1024 * 64 * 2);
  unsigned short* attn_hi = (unsigned short*)take((size_t)NTOK * DMODEL * 2);
  unsigned short* attn_lo = (unsigned short*)take((size_t)NTOK * DMODEL * 2);
  float* x1    = (float*)take((size_t)NTOK * DMODEL * 4);
  float* h2f   = (float*)take((size_t)NTOK * DMODEL * 4);
  unsigned short* h2bf = (unsigned short*)take((size_t)NTOK * DMODEL * 2);
  unsigned short* Xg   = (unsigned short*)take((size_t)MAXROWS * DMODEL * 2);
  unsigned short* hid  = (unsigned short*)take((size_t)MAXROWS * DFF * 2);
  float* eout  = (float*)take((size_t)MAXROWS * DMODEL * 4);
  int*   tok_e   = (int*)take(4096 * 4);
  float* tok_g   = (float*)take(4096 * 4);
  int*   tok_pos = (int*)take(4096 * 4);
  int*   counts  = (int*)take(64);
  int*   fill    = (int*)take(64);
  int*   off_pad = (int*)take(64);
  int*   tile_map = (int*)take(256);

  init_kernel<<<1, 64, 0, stream>>>(counts, fill);
  ln_kernel<<<NTOK, 256, 0, stream>>>(x, ln1g, ln1b, h1_hi, h1_lo, nullptr);
  transpose_w<1><<<dim3(32, 32, 1), dim3(32, 8), 0, stream>>>(wq, wqkv_hi, wqkv_lo, 1024, 1024, 0, 0);
  transpose_w<1><<<dim3(8, 32, 1), dim3(32, 8), 0, stream>>>(wk, wqkv_hi + (size_t)1024 * 1024, wqkv_lo + (size_t)1024 * 1024, 1024, 256, 0, 0);
  transpose_w<1><<<dim3(8, 32, 1), dim3(32, 8), 0, stream>>>(wv, wqkv_hi + (size_t)1280 * 1024, wqkv_lo + (size_t)1280 * 1024, 1024, 256, 0, 0);
  transpose_w<1><<<dim3(32, 32, 1), dim3(32, 8), 0, stream>>>(wo, woT_hi, woT_lo, 1024, 1024, 0, 0);
  transpose_w<0><<<dim3(128, 32, 8), dim3(32, 8), 0, stream>>>(w1, w1t, nullptr, 1024, 4096, (long)1024 * 4096, (long)4096 * 1024);
  transpose_w<0><<<dim3(32, 128, 8), dim3(32, 8), 0, stream>>>(w2, w2t, nullptr, 4096, 1024, (long)4096 * 1024, (long)1024 * 4096);
  // qkv = h1 @ [wq|wk|wv], single-launch 3-term split
  gemm_split<0><<<dim3(12, 16), 256, 0, stream>>>(h1_hi, h1_lo, wqkv_hi, wqkv_lo, qkv, nullptr, 1536, 1024);
  rope_split<<<NTOK, 256, 0, stream>>>(qkv, q_hi, q_lo, k_hi, k_lo);
  vt_split<<<dim3(2, 32, 8), dim3(32, 8), 0, stream>>>(qkv, vt_hi, vt_lo);
  attn_mfma<<<512, 256, 0, stream>>>(q_hi, q_lo, k_hi, k_lo, vt_hi, vt_lo, attn_hi, attn_lo);
  // x1 = x + attn @ wo, single-launch 3-term split
  gemm_split<2><<<dim3(8, 16), 256, 0, stream>>>(attn_hi, attn_lo, woT_hi, woT_lo, x1, x, 1024, 1024);
  ln_kernel<<<NTOK, 256, 0, stream>>>(x1, ln2g, ln2b, h2bf, nullptr, h2f);
  router_kernel<<<NTOK, 64, 0, stream>>>(h2f, wg, tok_e, tok_g, counts);
  finalize_kernel<<<1, 64, 0, stream>>>(counts, off_pad, tile_map, out + (size_t)NTOK * DMODEL);
  scatter_kernel<<<4096, 256, 0, stream>>>(tok_e, off_pad, fill, tok_pos, h2bf, Xg);
  gemm_bt<3,1><<<dim3(32, MAXTILES), 256, 0, stream>>>(Xg, w1t, nullptr, hid, DFF, DMODEL, tile_map, (long)DFF * DMODEL);
  gemm_bt<0,1><<<dim3(8, MAXTILES), 256, 0, stream>>>(hid, w2t, eout, nullptr, DMODEL, DFF, tile_map, (long)DMODEL * DFF);
  combine_kernel<<<NTOK, 256, 0, stream>>>(x1, eout, tok_pos, tok_g, out);
}

// Round 3
// 754.963 us; speedup vs baseline: 1.4791x; 1.0042x over previous
//
#include <hip/hip_runtime.h>
#include <hip/hip_bf16.h>

#define NTOK   2048      // B*L
#define DMODEL 1024
#define NEXP   8
#define DFF    4096
#define MAXROWS 5120
#define MAXTILES 40

typedef __attribute__((ext_vector_type(8))) short short8;
typedef __attribute__((ext_vector_type(4))) float float4v;

__device__ __forceinline__ unsigned short f2bf(float f) {
  union { float f; unsigned u; } v; v.f = f;
  unsigned r = v.u + 0x7fffu + ((v.u >> 16) & 1u);
  return (unsigned short)(r >> 16);
}
__device__ __forceinline__ float bf2f(unsigned short h) {
  union { unsigned u; float f; } v; v.u = ((unsigned)h) << 16; return v.f;
}
__device__ __forceinline__ void gl_lds16(const void* g, void* l) {
  __builtin_amdgcn_global_load_lds((const __attribute__((address_space(1))) void*)g,
                                   (__attribute__((address_space(3))) void*)l, 16, 0, 0);
}

// ---------------- GEMM: C[M,N] = A[M,K](bf16) x B[N,K]^T(bf16), fp32 acc ---
// EPI: 0 C=acc ; 3 Cbf=bf16(gelu(acc))
// launch_bounds(256,4): 4 blocks/CU (32KB LDS ea, VGPR<=128) — latency hiding
template<int EPI, int EMAP>
__launch_bounds__(256, 4)
__global__ void gemm_bt(const unsigned short* __restrict__ A,
                        const unsigned short* __restrict__ B0,
                        float* __restrict__ C,
                        unsigned short* __restrict__ Cbf,
                        const int N, const int K,
                        const int* __restrict__ tmap, const long estride) {
  const int mtile = blockIdx.y;
  const unsigned short* B = B0;
  if (EMAP) {
    int e = tmap[mtile];
    if (e < 0) return;
    B += (size_t)e * (size_t)estride;
  }
  const int n0 = blockIdx.x * 128;
  const int m0 = mtile * 128;
  __shared__ unsigned short sA[128 * 64];
  __shared__ unsigned short sB[128 * 64];
  const int tid  = threadIdx.x;
  const int w    = tid >> 6;
  const int lane = tid & 63;
  const int quad = lane >> 4;
  const int r16  = lane & 15;
  const int wr   = w >> 1;
  const int wc   = w & 1;
  const int rl   = lane >> 3;
  const int csl  = lane & 7;
  const int cg   = csl ^ rl;
  float4v acc[4][4];
#pragma unroll
  for (int i = 0; i < 4; ++i)
#pragma unroll
    for (int j = 0; j < 4; ++j) acc[i][j] = float4v{0.f, 0.f, 0.f, 0.f};

  const unsigned short* Ab = A + (size_t)m0 * K + cg * 8;
  const unsigned short* Bb = B + (size_t)n0 * K + cg * 8;

  for (int k0 = 0; k0 < K; k0 += 64) {
    __syncthreads();
#pragma unroll
    for (int i = 0; i < 4; ++i) {
      const int j = w * 4 + i;
      gl_lds16(Ab + (size_t)(j * 8 + rl) * K + k0, (char*)sA + j * 1024);
      gl_lds16(Bb + (size_t)(j * 8 + rl) * K + k0, (char*)sB + j * 1024);
    }
    __syncthreads();
#pragma unroll
    for (int kc = 0; kc < 8; kc += 4) {
      short8 af[4], bq[4];
#pragma unroll
      for (int mt = 0; mt < 4; ++mt) {
        int r = wr * 64 + mt * 16 + r16;
        af[mt] = *(const short8*)(sA + ((r * 8 + ((kc + quad) ^ (r & 7))) * 8));
      }
#pragma unroll
      for (int nt = 0; nt < 4; ++nt) {
        int r = wc * 64 + nt * 16 + r16;
        bq[nt] = *(const short8*)(sB + ((r * 8 + ((kc + quad) ^ (r & 7))) * 8));
      }
#pragma unroll
      for (int mt = 0; mt < 4; ++mt)
#pragma unroll
        for (int nt = 0; nt < 4; ++nt)
          acc[mt][nt] = __builtin_amdgcn_mfma_f32_16x16x32_bf16(af[mt], bq[nt], acc[mt][nt], 0, 0, 0);
    }
  }
#pragma unroll
  for (int mt = 0; mt < 4; ++mt) {
#pragma unroll
    for (int nt = 0; nt < 4; ++nt) {
#pragma unroll
      for (int rg = 0; rg < 4; ++rg) {
        const int m = m0 + wr * 64 + mt * 16 + quad * 4 + rg;
        const int n = n0 + wc * 64 + nt * 16 + r16;
        const size_t idx = (size_t)m * N + n;
        const float v = acc[mt][nt][rg];
        if (EPI == 0) C[idx] = v;
        else {
          float ge = 0.5f * v * (1.0f + erff(v * 0.70710678118654752440f));
          Cbf[idx] = f2bf(ge);
        }
      }
    }
  }
}

// ------- split-bf16 GEMM: C = (Ah+Al)x(Bh+Bl)^T, 3 terms, single launch -----
// EPI: 0 C=acc ; 2 C = acc + R
template<int EPI>
__launch_bounds__(256, 2)
__global__ void gemm_split(const unsigned short* __restrict__ Ah,
                           const unsigned short* __restrict__ Al,
                           const unsigned short* __restrict__ Bh,
                           const unsigned short* __restrict__ Bl,
                           float* __restrict__ C, const float* __restrict__ R,
                           const int N, const int K) {
  const int n0 = blockIdx.x * 128;
  const int m0 = blockIdx.y * 128;
  __shared__ unsigned short sAh[128 * 64];
  __shared__ unsigned short sAl[128 * 64];
  __shared__ unsigned short sBh[128 * 64];
  __shared__ unsigned short sBl[128 * 64];
  const int tid  = threadIdx.x;
  const int w    = tid >> 6;
  const int lane = tid & 63;
  const int quad = lane >> 4;
  const int r16  = lane & 15;
  const int wr   = w >> 1;
  const int wc   = w & 1;
  const int rl   = lane >> 3;
  const int csl  = lane & 7;
  const int cg   = csl ^ rl;
  float4v acc[4][4];
#pragma unroll
  for (int i = 0; i < 4; ++i)
#pragma unroll
    for (int j = 0; j < 4; ++j) acc[i][j] = float4v{0.f, 0.f, 0.f, 0.f};

  const size_t aoff = (size_t)m0 * K + cg * 8;
  const size_t boff = (size_t)n0 * K + cg * 8;

  for (int k0 = 0; k0 < K; k0 += 64) {
    __syncthreads();
#pragma unroll
    for (int i = 0; i < 4; ++i) {
      const int j = w * 4 + i;
      const size_t ro = (size_t)(j * 8 + rl) * K + k0;
      gl_lds16(Ah + aoff + ro, (char*)sAh + j * 1024);
      gl_lds16(Al + aoff + ro, (char*)sAl + j * 1024);
      gl_lds16(Bh + boff + ro, (char*)sBh + j * 1024);
      gl_lds16(Bl + boff + ro, (char*)sBl + j * 1024);
    }
    __syncthreads();
#pragma unroll
    for (int kc = 0; kc < 8; kc += 4) {
      short8 afh[4], afl[4], bqh[4], bql[4];
#pragma unroll
      for (int mt = 0; mt < 4; ++mt) {
        int r = wr * 64 + mt * 16 + r16;
        int o = (r * 8 + ((kc + quad) ^ (r & 7))) * 8;
        afh[mt] = *(const short8*)(sAh + o);
        afl[mt] = *(const short8*)(sAl + o);
      }
#pragma unroll
      for (int nt = 0; nt < 4; ++nt) {
        int r = wc * 64 + nt * 16 + r16;
        int o = (r * 8 + ((kc + quad) ^ (r & 7))) * 8;
        bqh[nt] = *(const short8*)(sBh + o);
        bql[nt] = *(const short8*)(sBl + o);
      }
#pragma unroll
      for (int mt = 0; mt < 4; ++mt)
#pragma unroll
        for (int nt = 0; nt < 4; ++nt) {
          acc[mt][nt] = __builtin_amdgcn_mfma_f32_16x16x32_bf16(afh[mt], bqh[nt], acc[mt][nt], 0, 0, 0);
          acc[mt][nt] = __builtin_amdgcn_mfma_f32_16x16x32_bf16(afh[mt], bql[nt], acc[mt][nt], 0, 0, 0);
          acc[mt][nt] = __builtin_amdgcn_mfma_f32_16x16x32_bf16(afl[mt], bqh[nt], acc[mt][nt], 0, 0, 0);
        }
    }
  }
#pragma unroll
  for (int mt = 0; mt < 4; ++mt) {
#pragma unroll
    for (int nt = 0; nt < 4; ++nt) {
#pragma unroll
      for (int rg = 0; rg < 4; ++rg) {
        const int m = m0 + wr * 64 + mt * 16 + quad * 4 + rg;
        const int n = n0 + wc * 64 + nt * 16 + r16;
        const size_t idx = (size_t)m * N + n;
        const float v = acc[mt][nt][rg];
        if (EPI == 0) C[idx] = v;
        else C[idx] = v + R[idx];
      }
    }
  }
}

// ------ fp32 [K,N] -> bf16 [N,K] (hi, optional lo), 64x64, vectorized -------
template<int WLO>
__global__ void transpose_w(const float* __restrict__ in, unsigned short* __restrict__ oh,
                            unsigned short* __restrict__ ol, const int K, const int N,
                            const long istride, const long ostride) {
  const int bz = blockIdx.z;
  in += (size_t)bz * istride;
  oh += (size_t)bz * ostride;
  if (WLO) ol += (size_t)bz * ostride;
  __shared__ float t[64][65];
  const int n0 = blockIdx.x * 64;
  const int k0 = blockIdx.y * 64;
  const int tid = threadIdx.x;
  const int rr = tid >> 4;        // 0..15
  const int c4 = (tid & 15) * 4;  // 0..60
#pragma unroll
  for (int p = 0; p < 4; ++p) {
    const int row = p * 16 + rr;
    const float4 v = *(const float4*)(in + (size_t)(k0 + row) * N + n0 + c4);
    t[row][c4] = v.x; t[row][c4 + 1] = v.y; t[row][c4 + 2] = v.z; t[row][c4 + 3] = v.w;
  }
  __syncthreads();
#pragma unroll
  for (int p = 0; p < 4; ++p) {
    const int n = p * 16 + rr;
    float vs[4];
#pragma unroll
    for (int i = 0; i < 4; ++i) vs[i] = t[c4 + i][n];
    ushort4 h;
    h.x = f2bf(vs[0]); h.y = f2bf(vs[1]); h.z = f2bf(vs[2]); h.w = f2bf(vs[3]);
    const size_t o = (size_t)(n0 + n) * K + k0 + c4;
    *(ushort4*)(oh + o) = h;
    if (WLO) {
      ushort4 lo4;
      lo4.x = f2bf(vs[0] - bf2f(h.x));
      lo4.y = f2bf(vs[1] - bf2f(h.y));
      lo4.z = f2bf(vs[2] - bf2f(h.z));
      lo4.w = f2bf(vs[3] - bf2f(h.w));
      *(ushort4*)(ol + o) = lo4;
    }
  }
}

// ---------------- LayerNorm over D=1024 -------------------------------------
__global__ void ln_kernel(const float* __restrict__ x, const float* __restrict__ g,
                          const float* __restrict__ b, unsigned short* __restrict__ hi,
                          unsigned short* __restrict__ lo, float* __restrict__ f32o) {
  const int row = blockIdx.x;
  const int tid = threadIdx.x;
  const int w = tid >> 6, lane = tid & 63;
  const float4 v = *(const float4*)(x + (size_t)row * DMODEL + tid * 4);
  float s = v.x + v.y + v.z + v.w;
  float q = v.x * v.x + v.y * v.y + v.z * v.z + v.w * v.w;
#pragma unroll
  for (int o = 32; o; o >>= 1) { s += __shfl_xor(s, o); q += __shfl_xor(q, o); }
  __shared__ float red[8];
  if (lane == 0) { red[w] = s; red[4 + w] = q; }
  __syncthreads();
  s = red[0] + red[1] + red[2] + red[3];
  q = red[4] + red[5] + red[6] + red[7];
  const float mean = s * (1.0f / DMODEL);
  const float var = q * (1.0f / DMODEL) - mean * mean;
  const float rs = rsqrtf(var + 1e-5f);
  const float4 gg = *(const float4*)(g + tid * 4);
  const float4 bb = *(const float4*)(b + tid * 4);
  float y[4];
  y[0] = (v.x - mean) * rs * gg.x + bb.x;
  y[1] = (v.y - mean) * rs * gg.y + bb.y;
  y[2] = (v.z - mean) * rs * gg.z + bb.z;
  y[3] = (v.w - mean) * rs * gg.w + bb.w;
  const size_t base = (size_t)row * DMODEL + tid * 4;
#pragma unroll
  for (int i = 0; i < 4; ++i) {
    unsigned short h = f2bf(y[i]);
    hi[base + i] = h;
    if (lo) lo[base + i] = f2bf(y[i] - bf2f(h));
    if (f32o) f32o[base + i] = y[i];
  }
}

// -------- RoPE -> split-bf16 Q [bh][L][64], K [bkvh][L][64] -----------------
__global__ void rope_split(const float* __restrict__ qkv,
                           unsigned short* __restrict__ q_hi, unsigned short* __restrict__ q_lo,
                           unsigned short* __restrict__ k_hi, unsigned short* __restrict__ k_lo) {
  const int rowtok = blockIdx.x;
  const int b = rowtok >> 10;
  const int l = rowtok & 1023;
  const int tid = threadIdx.x;
  __shared__ float cb[32], sb[32];
  if (tid < 32) {
    float inv = powf(10000.0f, -(float)tid * (1.0f / 32.0f));
    float ang = (float)l * inv;
    cb[tid] = cosf(ang);
    sb[tid] = sinf(ang);
  }
  __syncthreads();
  const float* src = qkv + (size_t)rowtok * 1536;
#pragma unroll
  for (int it = 0; it < 5; ++it) {
    const int e = tid + it * 256;
    const int hh = e >> 6;
    const int d = e & 63;
    const int dm = d & 31;
    float val = src[e];
    float partner = (d < 32) ? -src[e + 32] : src[e - 32];
    float ov = val * cb[dm] + partner * sb[dm];
    unsigned short hv = f2bf(ov);
    unsigned short lv = f2bf(ov - bf2f(hv));
    if (hh < 16) {
      size_t idx = ((size_t)(b * 16 + hh) * 1024 + l) * 64 + d;
      q_hi[idx] = hv; q_lo[idx] = lv;
    } else {
      size_t idx = ((size_t)(b * 4 + (hh - 16)) * 1024 + l) * 64 + d;
      k_hi[idx] = hv; k_lo[idx] = lv;
    }
  }
}

// -------- V transpose: qkv v-part [L][64] -> bf16 hi/lo [bkvh][64][L] -------
__global__ void vt_split(const float* __restrict__ qkv,
                         unsigned short* __restrict__ vt_hi, unsigned short* __restrict__ vt_lo) {
  const int bkvh = blockIdx.z;
  const int b = bkvh >> 2;
  const int kvh = bkvh & 3;
  const float* src = qkv + (size_t)b * 1024 * 1536 + 1280 + kvh * 64;
  __shared__ float t[32][33];
  const int l0 = blockIdx.y * 32;
  const int d0 = blockIdx.x * 32;
  const int tx = threadIdx.x;
  const int ty = threadIdx.y;
#pragma unroll
  for (int i = 0; i < 4; ++i)
    t[ty + i * 8][tx] = src[(size_t)(l0 + ty + i * 8) * 1536 + d0 + tx];
  __syncthreads();
#pragma unroll
  for (int i = 0; i < 4; ++i) {
    float v = t[tx][ty + i * 8];
    size_t o = (size_t)bkvh * 65536 + (size_t)(d0 + ty + i * 8) * 1024 + l0 + tx;
    unsigned short h = f2bf(v);
    vt_hi[o] = h;
    vt_lo[o] = f2bf(v - bf2f(h));
  }
}

// ---------------- flash attention, split-bf16 MFMA, fp32 softmax ------------
__launch_bounds__(256, 2)
__global__ void attn_mfma(const unsigned short* __restrict__ q_hi, const unsigned short* __restrict__ q_lo,
                          const unsigned short* __restrict__ k_hi, const unsigned short* __restrict__ k_lo,
                          const unsigned short* __restrict__ vt_hi, const unsigned short* __restrict__ vt_lo,
                          unsigned short* __restrict__ ohi, unsigned short* __restrict__ olo) {
  const int blk = blockIdx.x;
  const int bh = blk & 31;               // (b,h)
  const int qt = 15 - (blk >> 5);        // long tiles dispatch first
  const int b = bh >> 4;
  const int h = bh & 15;
  const int kvbh = b * 4 + (h >> 2);
  const int q0 = qt * 64;
  const int tid = threadIdx.x;
  const int w = tid >> 6;
  const int lane = tid & 63;
  const int quad = lane >> 4;
  const int r16 = lane & 15;
  const int rl = lane >> 3;
  const int csl = lane & 7;
  const int cg = csl ^ rl;

  __shared__ unsigned short sK[2][64 * 64];
  __shared__ unsigned short sV[2][64 * 64];
  __shared__ unsigned short sP[2][64 * 64];

  short8 qfh[2], qfl[2];
  {
    const size_t qrow = ((size_t)bh * 1024 + q0 + w * 16 + r16) * 64 + quad * 8;
    qfh[0] = *(const short8*)(q_hi + qrow);
    qfh[1] = *(const short8*)(q_hi + qrow + 32);
    qfl[0] = *(const short8*)(q_lo + qrow);
    qfl[1] = *(const short8*)(q_lo + qrow + 32);
  }
  float4v O[4];
#pragma unroll
  for (int nt = 0; nt < 4; ++nt) O[nt] = float4v{0.f, 0.f, 0.f, 0.f};
  float m[4], l[4];
#pragma unroll
  for (int rg = 0; rg < 4; ++rg) { m[rg] = -__builtin_inff(); l[rg] = 0.f; }

  const unsigned short* khb = k_hi + (size_t)kvbh * 65536 + cg * 8;
  const unsigned short* klb = k_lo + (size_t)kvbh * 65536 + cg * 8;
  const unsigned short* vhb = vt_hi + (size_t)kvbh * 65536 + cg * 8;
  const unsigned short* vlb = vt_lo + (size_t)kvbh * 65536 + cg * 8;

  for (int c = 0; c <= qt; ++c) {
    __syncthreads();
#pragma unroll
    for (int j = 0; j < 2; ++j) {
      const int i = w * 2 + j;
      const int row = i * 8 + rl;
      gl_lds16(khb + (size_t)(c * 64 + row) * 64, (char*)sK[0] + i * 1024);
      gl_lds16(klb + (size_t)(c * 64 + row) * 64, (char*)sK[1] + i * 1024);
      gl_lds16(vhb + (size_t)row * 1024 + c * 64, (char*)sV[0] + i * 1024);
      gl_lds16(vlb + (size_t)row * 1024 + c * 64, (char*)sV[1] + i * 1024);
    }
    __syncthreads();

    float4v S[4];
#pragma unroll
    for (int nt = 0; nt < 4; ++nt) S[nt] = float4v{0.f, 0.f, 0.f, 0.f};
#pragma unroll
    for (int ks = 0; ks < 2; ++ks) {
#pragma unroll
      for (int nt = 0; nt < 4; ++nt) {
        const int r = nt * 16 + r16;
        const int o = (r * 8 + ((ks * 4 + quad) ^ (r & 7))) * 8;
        const short8 kh = *(const short8*)(sK[0] + o);
        const short8 kl = *(const short8*)(sK[1] + o);
        S[nt] = __builtin_amdgcn_mfma_f32_16x16x32_bf16(qfh[ks], kh, S[nt], 0, 0, 0);
        S[nt] = __builtin_amdgcn_mfma_f32_16x16x32_bf16(qfh[ks], kl, S[nt], 0, 0, 0);
        S[nt] = __builtin_amdgcn_mfma_f32_16x16x32_bf16(qfl[ks], kh, S[nt], 0, 0, 0);
      }
    }
    const float NEGINF = -__builtin_inff();
#pragma unroll
    for (int nt = 0; nt < 4; ++nt)
#pragma unroll
      for (int rg = 0; rg < 4; ++rg) S[nt][rg] *= 0.125f;
    if (c == qt) {
#pragma unroll
      for (int nt = 0; nt < 4; ++nt) {
        const int col = nt * 16 + r16;
#pragma unroll
        for (int rg = 0; rg < 4; ++rg) {
          const int row = w * 16 + quad * 4 + rg;
          if (col > row) S[nt][rg] = NEGINF;
        }
      }
    }
    float alpha[4], lsum[4];
#pragma unroll
    for (int rg = 0; rg < 4; ++rg) {
      float mx = fmaxf(fmaxf(S[0][rg], S[1][rg]), fmaxf(S[2][rg], S[3][rg]));
      mx = fmaxf(mx, __shfl_xor(mx, 1));
      mx = fmaxf(mx, __shfl_xor(mx, 2));
      mx = fmaxf(mx, __shfl_xor(mx, 4));
      mx = fmaxf(mx, __shfl_xor(mx, 8));
      const float mn = fmaxf(m[rg], mx);
      alpha[rg] = __expf(m[rg] - mn);
      m[rg] = mn;
      lsum[rg] = 0.f;
    }
#pragma unroll
    for (int nt = 0; nt < 4; ++nt)
#pragma unroll
      for (int rg = 0; rg < 4; ++rg) {
        const float e = __expf(S[nt][rg] - m[rg]);
        S[nt][rg] = e;
        lsum[rg] += e;
      }
#pragma unroll
    for (int rg = 0; rg < 4; ++rg) {
      float ls = lsum[rg];
      ls += __shfl_xor(ls, 1);
      ls += __shfl_xor(ls, 2);
      ls += __shfl_xor(ls, 4);
      ls += __shfl_xor(ls, 8);
      l[rg] = l[rg] * alpha[rg] + ls;
    }
#pragma unroll
    for (int nt = 0; nt < 4; ++nt) {
      const int key = nt * 16 + r16;
      const int chunk = key >> 3;
#pragma unroll
      for (int rg = 0; rg < 4; ++rg) {
        const int r = w * 16 + quad * 4 + rg;
        const int addr = r * 64 + ((chunk ^ (r & 7)) * 8) + (key & 7);
        const float e = S[nt][rg];
        const unsigned short hv = f2bf(e);
        sP[0][addr] = hv;
        sP[1][addr] = f2bf(e - bf2f(hv));
      }
    }
#pragma unroll
    for (int nt = 0; nt < 4; ++nt)
#pragma unroll
      for (int rg = 0; rg < 4; ++rg) O[nt][rg] *= alpha[rg];
#pragma unroll
    for (int ks = 0; ks < 2; ++ks) {
      const int rA = w * 16 + r16;
      const int oA = (rA * 8 + ((ks * 4 + quad) ^ (rA & 7))) * 8;
      const short8 ph = *(const short8*)(sP[0] + oA);
      const short8 pl = *(const short8*)(sP[1] + oA);
#pragma unroll
      for (int nt = 0; nt < 4; ++nt) {
        const int rv = nt * 16 + r16;
        const int ov = (rv * 8 + ((ks * 4 + quad) ^ (rv & 7))) * 8;
        const short8 vh = *(const short8*)(sV[0] + ov);
        const short8 vl = *(const short8*)(sV[1] + ov);
        O[nt] = __builtin_amdgcn_mfma_f32_16x16x32_bf16(ph, vh, O[nt], 0, 0, 0);
        O[nt] = __builtin_amdgcn_mfma_f32_16x16x32_bf16(ph, vl, O[nt], 0, 0, 0);
        O[nt] = __builtin_amdgcn_mfma_f32_16x16x32_bf16(pl, vh, O[nt], 0, 0, 0);
      }
    }
  }
#pragma unroll
  for (int nt = 0; nt < 4; ++nt) {
    const int col = h * 64 + nt * 16 + r16;
#pragma unroll
    for (int rg = 0; rg < 4; ++rg) {
      const int row = q0 + w * 16 + quad * 4 + rg;
      const float ovv = O[nt][rg] / l[rg];
      const size_t idx = ((size_t)b * 1024 + row) * DMODEL + col;
      const unsigned short hv = f2bf(ovv);
      ohi[idx] = hv;
      olo[idx] = f2bf(ovv - bf2f(hv));
    }
  }
}

// ---------------- router: fp32 logits, top-2, gates, counts -----------------
#define RED6SUM(X) { X += __shfl_xor(X,32); X += __shfl_xor(X,16); X += __shfl_xor(X,8); X += __shfl_xor(X,4); X += __shfl_xor(X,2); X += __shfl_xor(X,1); }

__global__ void router_kernel(const float* __restrict__ h2f, const float* __restrict__ wg,
                              int* __restrict__ tok_e, float* __restrict__ tok_g,
                              int* __restrict__ counts) {
  const int t = blockIdx.x;
  const int lane = threadIdx.x;
  float acc[8] = {0,0,0,0,0,0,0,0};
  const float* hr = h2f + (size_t)t * DMODEL;
  for (int d = lane; d < DMODEL; d += 64) {
    const float hv = hr[d];
    const float4 w0 = *(const float4*)(wg + d * 8);
    const float4 w1_ = *(const float4*)(wg + d * 8 + 4);
    acc[0] += hv * w0.x; acc[1] += hv * w0.y; acc[2] += hv * w0.z; acc[3] += hv * w0.w;
    acc[4] += hv * w1_.x; acc[5] += hv * w1_.y; acc[6] += hv * w1_.z; acc[7] += hv * w1_.w;
  }
#pragma unroll
  for (int e = 0; e < 8; ++e) { RED6SUM(acc[e]); }
  if (lane == 0) {
    int i0 = 0; float v0 = acc[0];
#pragma unroll
    for (int e = 1; e < 8; ++e) if (acc[e] > v0) { v0 = acc[e]; i0 = e; }
    int i1 = -1; float v1 = -__builtin_inff();
#pragma unroll
    for (int e = 0; e < 8; ++e) if (e != i0 && acc[e] > v1) { v1 = acc[e]; i1 = e; }
    const float ex = __expf(v1 - v0);
    const float den = 1.0f + ex;
    tok_e[t * 2] = i0; tok_e[t * 2 + 1] = i1;
    tok_g[t * 2] = 1.0f / den; tok_g[t * 2 + 1] = ex / den;
    atomicAdd(counts + i0, 1);
    atomicAdd(counts + i1, 1);
  }
}

__global__ void finalize_kernel(const int* __restrict__ counts, int* __restrict__ off_pad,
                                int* __restrict__ tile_map, float* __restrict__ lb_out) {
  if (threadIdx.x == 0 && blockIdx.x == 0) {
    int tile = 0, rowoff = 0;
    for (int e = 0; e < NEXP; ++e) {
      off_pad[e] = rowoff;
      const int c = counts[e];
      const int nt = (c + 127) >> 7;
      for (int i = 0; i < nt; ++i) tile_map[tile++] = e;
      rowoff += nt * 128;
    }
    for (; tile < MAXTILES; ++tile) tile_map[tile] = -1;
    float sacc = 0.f;
    for (int e = 0; e < NEXP; ++e) {
      const float cn = (float)counts[e] * (1.0f / 4096.0f);
      const float d = cn - 0.125f;
      sacc += d * d;
    }
    lb_out[0] = sacc * (1.0f / 8.0f);
  }
}

__global__ void scatter_kernel(const int* __restrict__ tok_e, const int* __restrict__ off_pad,
                               int* __restrict__ fill, int* __restrict__ tok_pos,
                               const unsigned short* __restrict__ h2bf, unsigned short* __restrict__ Xg) {
  const int slot = blockIdx.x;
  const int t = slot >> 1;
  __shared__ int sp;
  if (threadIdx.x == 0) {
    const int e = tok_e[slot];
    const int r = atomicAdd(fill + e, 1);
    const int ppos = off_pad[e] + r;
    tok_pos[slot] = ppos;
    sp = ppos;
  }
  __syncthreads();
  const int pos = sp;
  *(uint2*)(Xg + (size_t)pos * DMODEL + threadIdx.x * 4) =
      *(const uint2*)(h2bf + (size_t)t * DMODEL + threadIdx.x * 4);
}

__global__ void combine_kernel(const float* __restrict__ x1, const float* __restrict__ eout,
                               const int* __restrict__ tok_pos, const float* __restrict__ tok_g,
                               float* __restrict__ out) {
  const int t = blockIdx.x;
  const int tid = threadIdx.x;
  const int p0 = tok_pos[t * 2], p1 = tok_pos[t * 2 + 1];
  const float g0 = tok_g[t * 2], g1 = tok_g[t * 2 + 1];
  const size_t o = (size_t)t * DMODEL + tid * 4;
  const float4 a = *(const float4*)(x1 + o);
  const float4 e0 = *(const float4*)(eout + (size_t)p0 * DMODEL + tid * 4);
  const float4 e1 = *(const float4*)(eout + (size_t)p1 * DMODEL + tid * 4);
  float4 r;
  r.x = a.x + g0 * e0.x + g1 * e1.x;
  r.y = a.y + g0 * e0.y + g1 * e1.y;
  r.z = a.z + g0 * e0.z + g1 * e1.z;
  r.w = a.w + g0 * e0.w + g1 * e1.w;
  *(float4*)(out + o) = r;
}

__global__ void init_kernel(int* counts, int* fill) {
  const int t = threadIdx.x;
  if (t < 8) { counts[t] = 0; fill[t] = 0; }
}

extern "C" void kernel_launch(void* const* d_in, const int* in_sizes, int n_in,
                              void* d_out, int out_size, void* d_ws, size_t ws_size,
                              hipStream_t stream) {
  (void)in_sizes; (void)n_in; (void)out_size; (void)ws_size;
  const float* x    = (const float*)d_in[0];
  const float* wq   = (const float*)d_in[1];
  const float* wk   = (const float*)d_in[2];
  const float* wv   = (const float*)d_in[3];
  const float* wo   = (const float*)d_in[4];
  const float* wg   = (const float*)d_in[5];
  const float* w1   = (const float*)d_in[6];
  const float* w2   = (const float*)d_in[7];
  const float* ln1g = (const float*)d_in[8];
  const float* ln1b = (const float*)d_in[9];
  const float* ln2g = (const float*)d_in[10];
  const float* ln2b = (const float*)d_in[11];
  float* out = (float*)d_out;

  char* p = (char*)d_ws;
  auto take = [&](size_t n) { void* r = (void*)p; p += (n + 255) & ~(size_t)255; return r; };
  unsigned short* h1_hi   = (unsigned short*)take((size_t)NTOK * DMODEL * 2);
  unsigned short* h1_lo   = (unsigned short*)take((size_t)NTOK * DMODEL * 2);
  unsigned short* wqkv_hi = (unsigned short*)take((size_t)1536 * 1024 * 2);
  unsigned short* wqkv_lo = (unsigned short*)take((size_t)1536 * 1024 * 2);
  unsigned short* woT_hi  = (unsigned short*)take((size_t)1024 * 1024 * 2);
  unsigned short* woT_lo  = (unsigned short*)take((size_t)1024 * 1024 * 2);
  unsigned short* w1t     = (unsigned short*)take((size_t)NEXP * DFF * DMODEL * 2);
  unsigned short* w2t     = (unsigned short*)take((size_t)NEXP * DMODEL * DFF * 2);
  float* qkv   = (float*)take((size_t)NTOK * 1536 * 4);
  unsigned short* q_hi  = (unsigned short*)take((size_t)2 * 16 * 1024 * 64 * 2);
  unsigned short* q_lo  = (unsigned short*)take((size_t)2 * 16 * 1024 * 64 * 2);
  unsigned short* k_hi  = (unsigned short*)take((size_t)2 * 4 * 1024 * 64 * 2);
  unsigned short* k_lo  = (unsigned short*)take((size_t)2 * 4 * 1024 * 64 * 2);
  unsigned short* vt_hi = (unsigned short*)take((size_t)2 * 4 * 1024 * 64 * 2);
  unsigned short* vt_lo = (unsigned short*)take((size_t)2 * 4 * 1024 * 64 * 2);
  unsigned short* attn_hi = (unsigned short*)take((size_t)NTOK * DMODEL * 2);
  unsigned short* attn_lo = (unsigned short*)take((size_t)NTOK * DMODEL * 2);
  float* x1    = (float*)take((size_t)NTOK * DMODEL * 4);
  float* h2f   = (float*)take((size_t)NTOK * DMODEL * 4);
  unsigned short* h2bf = (unsigned short*)take((size_t)NTOK * DMODEL * 2);
  unsigned short* Xg   = (unsigned short*)take((size_t)MAXROWS * DMODEL * 2);
  unsigned short* hid  = (unsigned short*)take((size_t)MAXROWS * DFF * 2);
  float* eout  = (float*)take((size_t)MAXROWS * DMODEL * 4);
  int*   tok_e   = (int*)take(4096 * 4);
  float* tok_g   = (float*)take(4096 * 4);
  int*   tok_pos = (int*)take(4096 * 4);
  int*   counts  = (int*)take(64);
  int*   fill    = (int*)take(64);
  int*   off_pad = (int*)take(64);
  int*   tile_map = (int*)take(256);

  init_kernel<<<1, 64, 0, stream>>>(counts, fill);
  ln_kernel<<<NTOK, 256, 0, stream>>>(x, ln1g, ln1b, h1_hi, h1_lo, nullptr);
  transpose_w<1><<<dim3(16, 16, 1), 256, 0, stream>>>(wq, wqkv_hi, wqkv_lo, 1024, 1024, 0, 0);
  transpose_w<1><<<dim3(4, 16, 1), 256, 0, stream>>>(wk, wqkv_hi + (size_t)1024 * 1024, wqkv_lo + (size_t)1024 * 1024, 1024, 256, 0, 0);
  transpose_w<1><<<dim3(4, 16, 1), 256, 0, stream>>>(wv, wqkv_hi + (size_t)1280 * 1024, wqkv_lo + (size_t)1280 * 1024, 1024, 256, 0, 0);
  transpose_w<1><<<dim3(16, 16, 1), 256, 0, stream>>>(wo, woT_hi, woT_lo, 1024, 1024, 0, 0);
  transpose_w<0><<<dim3(64, 16, 8), 256, 0, stream>>>(w1, w1t, nullptr, 1024, 4096, (long)1024 * 4096, (long)4096 * 1024);
  transpose_w<0><<<dim3(16, 64, 8), 256, 0, stream>>>(w2, w2t, nullptr, 4096, 1024, (long)4096 * 1024, (long)1024 * 4096);
  // qkv = h1 @ [wq|wk|wv], single-launch 3-term split
  gemm_split<0><<<dim3(12, 16), 256, 0, stream>>>(h1_hi, h1_lo, wqkv_hi, wqkv_lo, qkv, nullptr, 1536, 1024);
  rope_split<<<NTOK, 256, 0, stream>>>(qkv, q_hi, q_lo, k_hi, k_lo);
  vt_split<<<dim3(2, 32, 8), dim3(32, 8), 0, stream>>>(qkv, vt_hi, vt_lo);
  attn_mfma<<<512, 256, 0, stream>>>(q_hi, q_lo, k_hi, k_lo, vt_hi, vt_lo, attn_hi, attn_lo);
  // x1 = x + attn @ wo, single-launch 3-term split
  gemm_split<2><<<dim3(8, 16), 256, 0, stream>>>(attn_hi, attn_lo, woT_hi, woT_lo, x1, x, 1024, 1024);
  ln_kernel<<<NTOK, 256, 0, stream>>>(x1, ln2g, ln2b, h2bf, nullptr, h2f);
  router_kernel<<<NTOK, 64, 0, stream>>>(h2f, wg, tok_e, tok_g, counts);
  finalize_kernel<<<1, 64, 0, stream>>>(counts, off_pad, tile_map, out + (size_t)NTOK * DMODEL);
  scatter_kernel<<<4096, 256, 0, stream>>>(tok_e, off_pad, fill, tok_pos, h2bf, Xg);
  gemm_bt<3,1><<<dim3(32, MAXTILES), 256, 0, stream>>>(Xg, w1t, nullptr, hid, DFF, DMODEL, tile_map, (long)DFF * DMODEL);
  gemm_bt<0,1><<<dim3(8, MAXTILES), 256, 0, stream>>>(hid, w2t, eout, nullptr, DMODEL, DFF, tile_map, (long)DMODEL * DFF);
  combine_kernel<<<NTOK, 256, 0, stream>>>(x1, eout, tok_pos, tok_g, out);
}